// Round 1
// baseline (458.600 us; speedup 1.0000x reference)
//
#include <hip/hip_runtime.h>
#include <math.h>

#define OVERLAP_THRESH 0.35f
#define VALID_THRESH   0.2f
#define NEGPOS         7
#define TMAX           64

__device__ __forceinline__ float sl1(float x) {
    float ax = fabsf(x);
    return ax < 1.0f ? 0.5f * ax * ax : ax - 0.5f;
}

// ---------------- K2: per-(b,t) best prior (argmax over P, first-occurrence) ----------
__global__ void best_prior_kernel(const float* __restrict__ priors,
                                  const float* __restrict__ targets,
                                  int P, int T, int B,
                                  int* __restrict__ bpi, int* __restrict__ valid,
                                  int* __restrict__ any_valid) {
    int wid  = blockIdx.x * (blockDim.x >> 6) + (threadIdx.x >> 6);
    int lane = threadIdx.x & 63;
    if (wid >= B * T) return;
    int b = wid / T, t = wid % T;
    const float* tg = targets + ((size_t)b * T + t) * 15;
    float tx1 = tg[0], ty1 = tg[1], tx2 = tg[2], ty2 = tg[3];
    float ta = (tx2 - tx1) * (ty2 - ty1);

    float best = -1.0f; int bestp = 0;
    for (int p = lane; p < P; p += 64) {
        float4 pr = ((const float4*)priors)[p];
        float hw = pr.z * 0.5f, hh = pr.w * 0.5f;
        float px1 = pr.x - hw, py1 = pr.y - hh;
        float px2 = pr.x + hw, py2 = pr.y + hh;
        float pa = (px2 - px1) * (py2 - py1);
        float iw = fmaxf(fminf(tx2, px2) - fmaxf(tx1, px1), 0.0f);
        float ih = fmaxf(fminf(ty2, py2) - fmaxf(ty1, py1), 0.0f);
        float inter = iw * ih;
        float iou = inter / (ta + pa - inter);
        if (iou > best) { best = iou; bestp = p; }   // strict > keeps lowest p per lane
    }
    for (int off = 32; off; off >>= 1) {
        float o2 = __shfl_down(best, off);
        int   p2 = __shfl_down(bestp, off);
        if (o2 > best || (o2 == best && p2 < bestp)) { best = o2; bestp = p2; }
    }
    if (lane == 0) {
        bpi[wid] = bestp;
        int v = (best >= VALID_THRESH) ? 1 : 0;
        valid[wid] = v;
        if (v) atomicOr(&any_valid[b], 1);
    }
}

// ---------------- K3: per-(b,p) match + per-prior losses -----------------------------
__global__ void match_loss_kernel(const float* __restrict__ priors,
                                  const float* __restrict__ targets,
                                  const float* __restrict__ loc_data,
                                  const float* __restrict__ conf_data,
                                  const float* __restrict__ landm_data,
                                  const int* __restrict__ bpi,
                                  const int* __restrict__ valid,
                                  const int* __restrict__ any_valid,
                                  int P, int T,
                                  float* __restrict__ rank_loss,
                                  int* __restrict__ num_pos,     // [B]
                                  int* __restrict__ total_pos1,  // [1]
                                  float* __restrict__ acc)       // [ll, llm, ce_pos, ce_neg]
{
    int b   = blockIdx.y;
    int tid = threadIdx.x;
    int p   = blockIdx.x * blockDim.x + tid;

    __shared__ float s_box[TMAX][4];
    __shared__ float s_area[TMAX], s_lab[TMAX];
    __shared__ float s_lm[TMAX][10];
    __shared__ int   s_bpi[TMAX], s_valid[TMAX];
    __shared__ int   s_av;
    __shared__ float s_ll, s_llm, s_cep;
    __shared__ int   s_np, s_np1;

    if (tid == 0) { s_av = any_valid[b]; s_ll = 0.f; s_llm = 0.f; s_cep = 0.f; s_np = 0; s_np1 = 0; }
    if (tid < T) {
        const float* tg = targets + ((size_t)b * T + tid) * 15;
        float x1 = tg[0], y1 = tg[1], x2 = tg[2], y2 = tg[3];
        s_box[tid][0] = x1; s_box[tid][1] = y1; s_box[tid][2] = x2; s_box[tid][3] = y2;
        s_area[tid] = (x2 - x1) * (y2 - y1);
        #pragma unroll
        for (int k = 0; k < 10; k++) s_lm[tid][k] = tg[4 + k];
        s_lab[tid]   = tg[14];
        s_bpi[tid]   = bpi[b * T + tid];
        s_valid[tid] = valid[b * T + tid];
    }
    __syncthreads();

    if (p < P) {
        float4 pr = ((const float4*)priors)[p];
        float hw = pr.z * 0.5f, hh = pr.w * 0.5f;
        float px1 = pr.x - hw, py1 = pr.y - hh;
        float px2 = pr.x + hw, py2 = pr.y + hh;
        float pa = (px2 - px1) * (py2 - py1);

        // max/argmax over truths (first occurrence -> strict >)
        float best = -1.0f; int bt = 0;
        for (int t = 0; t < T; t++) {
            float iw = fmaxf(fminf(s_box[t][2], px2) - fmaxf(s_box[t][0], px1), 0.0f);
            float ih = fmaxf(fminf(s_box[t][3], py2) - fmaxf(s_box[t][1], py1), 0.0f);
            float inter = iw * ih;
            float iou = inter / (s_area[t] + pa - inter);
            if (iou > best) { best = iou; bt = t; }
        }
        // scatter overrides: idx set (last write wins -> largest t), overlap max 2.0 (valid only)
        int ovr = -1, any2 = 0;
        for (int t = 0; t < T; t++) {
            if (s_bpi[t] == p) { ovr = t; if (s_valid[t]) any2 = 1; }
        }
        if (ovr >= 0) bt = ovr;
        if (any2)     best = 2.0f;

        float lab  = s_lab[bt];
        float conf = (s_av && best >= OVERLAP_THRESH) ? lab : 0.0f;
        int   ci   = (int)conf;          // astype(int32) truncation
        bool  pos  = (ci != 0);
        bool  pos1 = (ci > 0);

        // cross-entropy: logsumexp - logit[target], target = pos ? 1 : 0
        const float* cd = conf_data + ((size_t)b * P + p) * 2;
        float c0 = cd[0], c1 = cd[1];
        float mx = fmaxf(c0, c1);
        float lse = mx + logf(expf(c0 - mx) + expf(c1 - mx));
        float ce  = lse - (pos ? c1 : c0);
        rank_loss[(size_t)b * P + p] = pos ? 0.0f : fmaxf(ce, 0.0f);

        if (pos) {
            const float* mb = s_box[bt];
            float gx = ((mb[0] + mb[2]) * 0.5f - pr.x) / (0.1f * pr.z);
            float gy = ((mb[1] + mb[3]) * 0.5f - pr.y) / (0.1f * pr.w);
            float gw = logf((mb[2] - mb[0]) / pr.z) / 0.2f;
            float gh = logf((mb[3] - mb[1]) / pr.w) / 0.2f;
            const float* ld = loc_data + ((size_t)b * P + p) * 4;
            float ll = sl1(ld[0] - gx) + sl1(ld[1] - gy) + sl1(ld[2] - gw) + sl1(ld[3] - gh);
            atomicAdd(&s_ll, ll);
            atomicAdd(&s_cep, ce);
            atomicAdd(&s_np, 1);
        }
        if (pos1) {
            const float* lmd = landm_data + ((size_t)b * P + p) * 10;
            float sx = 1.0f / (0.1f * pr.z), sy = 1.0f / (0.1f * pr.w);
            float s = 0.0f;
            #pragma unroll
            for (int k = 0; k < 5; k++) {
                float gx = (s_lm[bt][2 * k]     - pr.x) * sx;
                float gy = (s_lm[bt][2 * k + 1] - pr.y) * sy;
                s += sl1(lmd[2 * k] - gx) + sl1(lmd[2 * k + 1] - gy);
            }
            atomicAdd(&s_llm, s);
            atomicAdd(&s_np1, 1);
        }
    }
    __syncthreads();
    if (tid == 0) {
        if (s_np)  { atomicAdd(&num_pos[b], s_np); atomicAdd(&acc[0], s_ll); atomicAdd(&acc[2], s_cep); }
        if (s_np1) { atomicAdd(total_pos1, s_np1); atomicAdd(&acc[1], s_llm); }
    }
}

// ---------------- K4: per-batch exact sum of top-K rank_loss via radix select --------
__global__ void topk_kernel(const float* __restrict__ rank_loss,
                            const int* __restrict__ num_pos,
                            int P, float* __restrict__ acc) {
    int b = blockIdx.x;
    int tid = threadIdx.x;
    long long Kll = (long long)num_pos[b] * NEGPOS;
    int K = (Kll > P - 1) ? (P - 1) : (int)Kll;
    if (K <= 0) return;

    __shared__ int      hist[256];
    __shared__ unsigned s_prefix;
    __shared__ int      s_r;
    __shared__ float    s_sum[4];
    __shared__ int      s_cnt[4];

    const float* v = rank_loss + (size_t)b * P;
    if (tid == 0) { s_prefix = 0u; s_r = K; }
    __syncthreads();

    for (int shift = 24; shift >= 0; shift -= 8) {
        for (int i = tid; i < 256; i += blockDim.x) hist[i] = 0;
        __syncthreads();
        unsigned prefix = s_prefix;
        unsigned hm = (shift == 24) ? 0u : (0xFFFFFFFFu << (shift + 8));
        for (int i = tid; i < P; i += blockDim.x) {
            unsigned u = __float_as_uint(v[i]);
            if ((u & hm) == prefix) atomicAdd(&hist[(u >> shift) & 255], 1);
        }
        __syncthreads();
        if (tid == 0) {
            int r = s_r, cum = 0, d;
            for (d = 255; d >= 0; d--) {
                int c = hist[d];
                if (cum + c >= r) break;
                cum += c;
            }
            if (d < 0) d = 0;
            s_prefix = prefix | ((unsigned)d << shift);
            s_r = r - cum;
        }
        __syncthreads();
    }
    float tau = __uint_as_float(s_prefix);

    float sum = 0.0f; int cnt = 0;
    for (int i = tid; i < P; i += blockDim.x) {
        float x = v[i];
        if (x > tau) { sum += x; cnt++; }
    }
    for (int off = 32; off; off >>= 1) {
        sum += __shfl_down(sum, off);
        cnt += __shfl_down(cnt, off);
    }
    int wv = tid >> 6;
    if ((tid & 63) == 0) { s_sum[wv] = sum; s_cnt[wv] = cnt; }
    __syncthreads();
    if (tid == 0) {
        float st = 0.f; int ct = 0;
        int nw = blockDim.x >> 6;
        for (int i = 0; i < nw; i++) { st += s_sum[i]; ct += s_cnt[i]; }
        atomicAdd(&acc[3], st + (float)(K - ct) * tau);
    }
}

// ---------------- K5: finalize -------------------------------------------------------
__global__ void finalize_kernel(const int* __restrict__ num_pos,
                                const int* __restrict__ total_pos1,
                                const float* __restrict__ acc,
                                int B, float* __restrict__ out) {
    int tp = 0;
    for (int b = 0; b < B; b++) tp += num_pos[b];
    float N  = fmaxf((float)tp, 1.0f);
    float N1 = fmaxf((float)(*total_pos1), 1.0f);
    out[0] = acc[0] / N;                 // loss_l / N
    out[1] = (acc[2] + acc[3]) / N;      // loss_c / N
    out[2] = acc[1] / N1;                // loss_landm / N1
}

extern "C" void kernel_launch(void* const* d_in, const int* in_sizes, int n_in,
                              void* d_out, int out_size, void* d_ws, size_t ws_size,
                              hipStream_t stream) {
    const float* loc_data   = (const float*)d_in[0];
    const float* conf_data  = (const float*)d_in[1];
    const float* landm_data = (const float*)d_in[2];
    const float* priors     = (const float*)d_in[3];
    const float* targets    = (const float*)d_in[4];
    float* out = (float*)d_out;

    int P  = in_sizes[3] / 4;
    int BP = in_sizes[0] / 4;
    int B  = BP / P;
    int T  = in_sizes[4] / (B * 15);

    char* ws = (char*)d_ws;
    float* rank_loss = (float*)ws;
    size_t off = (size_t)B * P * sizeof(float);
    int* bpi        = (int*)(ws + off); off += (size_t)B * T * sizeof(int);
    int* valid      = (int*)(ws + off); off += (size_t)B * T * sizeof(int);
    int* any_valid  = (int*)(ws + off); off += (size_t)B * sizeof(int);
    int* num_pos    = (int*)(ws + off); off += (size_t)B * sizeof(int);
    int* total_pos1 = (int*)(ws + off); off += sizeof(int);
    float* acc      = (float*)(ws + off); off += 4 * sizeof(float);

    // zero the accumulator region (any_valid .. acc end) every call
    size_t zbytes = (size_t)((char*)(acc + 4) - (char*)any_valid);
    hipMemsetAsync(any_valid, 0, zbytes, stream);

    int waves  = B * T;
    int blocks2 = (waves + 3) / 4;  // 4 waves / 256-thread block
    best_prior_kernel<<<blocks2, 256, 0, stream>>>(priors, targets, P, T, B,
                                                   bpi, valid, any_valid);

    dim3 g3((P + 255) / 256, B);
    match_loss_kernel<<<g3, 256, 0, stream>>>(priors, targets, loc_data, conf_data,
                                              landm_data, bpi, valid, any_valid,
                                              P, T, rank_loss, num_pos, total_pos1, acc);

    topk_kernel<<<B, 256, 0, stream>>>(rank_loss, num_pos, P, acc);

    finalize_kernel<<<1, 1, 0, stream>>>(num_pos, total_pos1, acc, B, out);
}

// Round 2
// 281.526 us; speedup vs baseline: 1.6290x; 1.6290x over previous
//
#include <hip/hip_runtime.h>
#include <math.h>

#define OVERLAP_THRESH 0.35f
#define VALID_THRESH   0.2f
#define NEGPOS         7
#define TMAX           64
#define NCHUNK         16   // waves per (b,t) argmax

__device__ __forceinline__ float sl1(float x) {
    float ax = fabsf(x);
    return ax < 1.0f ? 0.5f * ax * ax : ax - 0.5f;
}

// ---------------- K2a: partial best-prior, split-K over priors -----------------------
// key = (iou_bits << 32) | (0xFFFFFFFF - p): max-key == argmax with lowest-p tie-break
__global__ void best_prior_partial_kernel(const float* __restrict__ priors,
                                          const float* __restrict__ targets,
                                          int P, int T,
                                          unsigned long long* __restrict__ keys) {
    int wid  = blockIdx.x * (blockDim.x >> 6) + (threadIdx.x >> 6);
    int lane = threadIdx.x & 63;
    int bt    = wid / NCHUNK;
    int chunk = wid % NCHUNK;
    int b = bt / T, t = bt % T;

    const float* tg = targets + ((size_t)b * T + t) * 15;
    float tx1 = tg[0], ty1 = tg[1], tx2 = tg[2], ty2 = tg[3];
    float ta = (tx2 - tx1) * (ty2 - ty1);

    int cs = P / NCHUNK;            // 2048
    int p0 = chunk * cs;
    float best = -1.0f; int bestp = p0;
    for (int p = p0 + lane; p < p0 + cs; p += 64) {
        float4 pr = ((const float4*)priors)[p];
        float hw = pr.z * 0.5f, hh = pr.w * 0.5f;
        float px1 = pr.x - hw, py1 = pr.y - hh;
        float px2 = pr.x + hw, py2 = pr.y + hh;
        float pa = (px2 - px1) * (py2 - py1);
        float iw = fmaxf(fminf(tx2, px2) - fmaxf(tx1, px1), 0.0f);
        float ih = fmaxf(fminf(ty2, py2) - fmaxf(ty1, py1), 0.0f);
        float inter = iw * ih;
        float iou = inter / (ta + pa - inter);
        if (iou > best) { best = iou; bestp = p; }   // strict >: lowest p per lane
    }
    unsigned long long key =
        ((unsigned long long)__float_as_uint(fmaxf(best, 0.0f)) << 32) |
        (unsigned long long)(0xFFFFFFFFu - (unsigned)bestp);
    for (int off = 32; off; off >>= 1) {
        unsigned long long k2 = __shfl_down(key, off);
        if (k2 > key) key = k2;
    }
    if (lane == 0) atomicMax(&keys[bt], key);
}

// ---------------- K2b: unpack keys -> bpi / valid / any_valid ------------------------
__global__ void best_prior_unpack_kernel(const unsigned long long* __restrict__ keys,
                                         int T, int BT,
                                         int* __restrict__ bpi, int* __restrict__ valid,
                                         int* __restrict__ any_valid) {
    int i = blockIdx.x * blockDim.x + threadIdx.x;
    if (i >= BT) return;
    unsigned long long k = keys[i];
    bpi[i] = (int)(0xFFFFFFFFu - (unsigned)(k & 0xFFFFFFFFull));
    float iou = __uint_as_float((unsigned)(k >> 32));
    int v = (iou >= VALID_THRESH) ? 1 : 0;
    valid[i] = v;
    if (v) atomicOr(&any_valid[i / T], 1);
}

// ---------------- K3: per-(b,p) match + per-prior losses -----------------------------
__global__ void match_loss_kernel(const float* __restrict__ priors,
                                  const float* __restrict__ targets,
                                  const float* __restrict__ loc_data,
                                  const float* __restrict__ conf_data,
                                  const float* __restrict__ landm_data,
                                  const int* __restrict__ bpi,
                                  const int* __restrict__ valid,
                                  const int* __restrict__ any_valid,
                                  int P, int T,
                                  float* __restrict__ rank_loss,
                                  int* __restrict__ num_pos,     // [B]
                                  int* __restrict__ total_pos1,  // [1]
                                  float* __restrict__ acc)       // [ll, llm, ce_pos, ce_neg]
{
    int b   = blockIdx.y;
    int tid = threadIdx.x;
    int p   = blockIdx.x * blockDim.x + tid;

    __shared__ float s_box[TMAX][4];
    __shared__ float s_area[TMAX], s_lab[TMAX];
    __shared__ float s_lm[TMAX][10];
    __shared__ int   s_bpi[TMAX], s_valid[TMAX];
    __shared__ int   s_av;
    __shared__ float s_ll, s_llm, s_cep;
    __shared__ int   s_np, s_np1;

    if (tid == 0) { s_av = any_valid[b]; s_ll = 0.f; s_llm = 0.f; s_cep = 0.f; s_np = 0; s_np1 = 0; }
    if (tid < T) {
        const float* tg = targets + ((size_t)b * T + tid) * 15;
        float x1 = tg[0], y1 = tg[1], x2 = tg[2], y2 = tg[3];
        s_box[tid][0] = x1; s_box[tid][1] = y1; s_box[tid][2] = x2; s_box[tid][3] = y2;
        s_area[tid] = (x2 - x1) * (y2 - y1);
        #pragma unroll
        for (int k = 0; k < 10; k++) s_lm[tid][k] = tg[4 + k];
        s_lab[tid]   = tg[14];
        s_bpi[tid]   = bpi[b * T + tid];
        s_valid[tid] = valid[b * T + tid];
    }
    __syncthreads();

    if (p < P) {
        float4 pr = ((const float4*)priors)[p];
        float hw = pr.z * 0.5f, hh = pr.w * 0.5f;
        float px1 = pr.x - hw, py1 = pr.y - hh;
        float px2 = pr.x + hw, py2 = pr.y + hh;
        float pa = (px2 - px1) * (py2 - py1);

        // max/argmax over truths (first occurrence -> strict >)
        float best = -1.0f; int bt = 0;
        for (int t = 0; t < T; t++) {
            float iw = fmaxf(fminf(s_box[t][2], px2) - fmaxf(s_box[t][0], px1), 0.0f);
            float ih = fmaxf(fminf(s_box[t][3], py2) - fmaxf(s_box[t][1], py1), 0.0f);
            float inter = iw * ih;
            float iou = inter / (s_area[t] + pa - inter);
            if (iou > best) { best = iou; bt = t; }
        }
        // scatter overrides: idx set (last write wins -> largest t), overlap max 2.0 (valid only)
        int ovr = -1, any2 = 0;
        for (int t = 0; t < T; t++) {
            if (s_bpi[t] == p) { ovr = t; if (s_valid[t]) any2 = 1; }
        }
        if (ovr >= 0) bt = ovr;
        if (any2)     best = 2.0f;

        float lab  = s_lab[bt];
        float conf = (s_av && best >= OVERLAP_THRESH) ? lab : 0.0f;
        int   ci   = (int)conf;          // astype(int32) truncation
        bool  pos  = (ci != 0);
        bool  pos1 = (ci > 0);

        // cross-entropy: logsumexp - logit[target], target = pos ? 1 : 0
        const float* cd = conf_data + ((size_t)b * P + p) * 2;
        float c0 = cd[0], c1 = cd[1];
        float mx = fmaxf(c0, c1);
        float lse = mx + logf(expf(c0 - mx) + expf(c1 - mx));
        float ce  = lse - (pos ? c1 : c0);
        rank_loss[(size_t)b * P + p] = pos ? 0.0f : fmaxf(ce, 0.0f);

        if (pos) {
            const float* mb = s_box[bt];
            float gx = ((mb[0] + mb[2]) * 0.5f - pr.x) / (0.1f * pr.z);
            float gy = ((mb[1] + mb[3]) * 0.5f - pr.y) / (0.1f * pr.w);
            float gw = logf((mb[2] - mb[0]) / pr.z) / 0.2f;
            float gh = logf((mb[3] - mb[1]) / pr.w) / 0.2f;
            const float* ld = loc_data + ((size_t)b * P + p) * 4;
            float ll = sl1(ld[0] - gx) + sl1(ld[1] - gy) + sl1(ld[2] - gw) + sl1(ld[3] - gh);
            atomicAdd(&s_ll, ll);
            atomicAdd(&s_cep, ce);
            atomicAdd(&s_np, 1);
        }
        if (pos1) {
            const float* lmd = landm_data + ((size_t)b * P + p) * 10;
            float sx = 1.0f / (0.1f * pr.z), sy = 1.0f / (0.1f * pr.w);
            float s = 0.0f;
            #pragma unroll
            for (int k = 0; k < 5; k++) {
                float gx = (s_lm[bt][2 * k]     - pr.x) * sx;
                float gy = (s_lm[bt][2 * k + 1] - pr.y) * sy;
                s += sl1(lmd[2 * k] - gx) + sl1(lmd[2 * k + 1] - gy);
            }
            atomicAdd(&s_llm, s);
            atomicAdd(&s_np1, 1);
        }
    }
    __syncthreads();
    if (tid == 0) {
        if (s_np)  { atomicAdd(&num_pos[b], s_np); atomicAdd(&acc[0], s_ll); atomicAdd(&acc[2], s_cep); }
        if (s_np1) { atomicAdd(total_pos1, s_np1); atomicAdd(&acc[1], s_llm); }
    }
}

// ---------------- K4: per-batch exact sum of top-K rank_loss via radix select --------
__global__ void topk_kernel(const float* __restrict__ rank_loss,
                            const int* __restrict__ num_pos,
                            int P, float* __restrict__ acc) {
    int b = blockIdx.x;
    int tid = threadIdx.x;
    long long Kll = (long long)num_pos[b] * NEGPOS;
    int K = (Kll > P - 1) ? (P - 1) : (int)Kll;
    if (K <= 0) return;

    __shared__ int      hist[256];
    __shared__ unsigned s_prefix;
    __shared__ int      s_r;
    __shared__ float    s_sum[16];
    __shared__ int      s_cnt[16];

    const float* v = rank_loss + (size_t)b * P;
    if (tid == 0) { s_prefix = 0u; s_r = K; }
    __syncthreads();

    for (int shift = 24; shift >= 0; shift -= 8) {
        for (int i = tid; i < 256; i += blockDim.x) hist[i] = 0;
        __syncthreads();
        unsigned prefix = s_prefix;
        unsigned hm = (shift == 24) ? 0u : (0xFFFFFFFFu << (shift + 8));
        for (int i = tid; i < P; i += blockDim.x) {
            unsigned u = __float_as_uint(v[i]);
            if ((u & hm) == prefix) atomicAdd(&hist[(u >> shift) & 255], 1);
        }
        __syncthreads();
        if (tid == 0) {
            int r = s_r, cum = 0, d;
            for (d = 255; d >= 0; d--) {
                int c = hist[d];
                if (cum + c >= r) break;
                cum += c;
            }
            if (d < 0) d = 0;
            s_prefix = prefix | ((unsigned)d << shift);
            s_r = r - cum;
        }
        __syncthreads();
    }
    float tau = __uint_as_float(s_prefix);

    float sum = 0.0f; int cnt = 0;
    for (int i = tid; i < P; i += blockDim.x) {
        float x = v[i];
        if (x > tau) { sum += x; cnt++; }
    }
    for (int off = 32; off; off >>= 1) {
        sum += __shfl_down(sum, off);
        cnt += __shfl_down(cnt, off);
    }
    int wv = tid >> 6;
    if ((tid & 63) == 0) { s_sum[wv] = sum; s_cnt[wv] = cnt; }
    __syncthreads();
    if (tid == 0) {
        float st = 0.f; int ct = 0;
        int nw = blockDim.x >> 6;
        for (int i = 0; i < nw; i++) { st += s_sum[i]; ct += s_cnt[i]; }
        atomicAdd(&acc[3], st + (float)(K - ct) * tau);
    }
}

// ---------------- K5: finalize -------------------------------------------------------
__global__ void finalize_kernel(const int* __restrict__ num_pos,
                                const int* __restrict__ total_pos1,
                                const float* __restrict__ acc,
                                int B, float* __restrict__ out) {
    int tp = 0;
    for (int b = 0; b < B; b++) tp += num_pos[b];
    float N  = fmaxf((float)tp, 1.0f);
    float N1 = fmaxf((float)(*total_pos1), 1.0f);
    out[0] = acc[0] / N;                 // loss_l / N
    out[1] = (acc[2] + acc[3]) / N;      // loss_c / N
    out[2] = acc[1] / N1;                // loss_landm / N1
}

extern "C" void kernel_launch(void* const* d_in, const int* in_sizes, int n_in,
                              void* d_out, int out_size, void* d_ws, size_t ws_size,
                              hipStream_t stream) {
    const float* loc_data   = (const float*)d_in[0];
    const float* conf_data  = (const float*)d_in[1];
    const float* landm_data = (const float*)d_in[2];
    const float* priors     = (const float*)d_in[3];
    const float* targets    = (const float*)d_in[4];
    float* out = (float*)d_out;

    int P  = in_sizes[3] / 4;
    int BP = in_sizes[0] / 4;
    int B  = BP / P;
    int T  = in_sizes[4] / (B * 15);
    int BT = B * T;

    char* ws = (char*)d_ws;
    float* rank_loss = (float*)ws;
    size_t off = (size_t)B * P * sizeof(float);
    // zeroed region starts here
    unsigned long long* keys = (unsigned long long*)(ws + off); off += (size_t)BT * sizeof(unsigned long long);
    int* bpi        = (int*)(ws + off); off += (size_t)BT * sizeof(int);
    int* valid      = (int*)(ws + off); off += (size_t)BT * sizeof(int);
    int* any_valid  = (int*)(ws + off); off += (size_t)B * sizeof(int);
    int* num_pos    = (int*)(ws + off); off += (size_t)B * sizeof(int);
    int* total_pos1 = (int*)(ws + off); off += sizeof(int);
    float* acc      = (float*)(ws + off); off += 4 * sizeof(float);

    size_t zbytes = (size_t)((char*)(acc + 4) - (char*)keys);
    hipMemsetAsync(keys, 0, zbytes, stream);

    // K2a: split-K best-prior. BT*NCHUNK waves, 4 waves/block.
    int waves   = BT * NCHUNK;
    int blocks2 = (waves + 3) / 4;
    best_prior_partial_kernel<<<blocks2, 256, 0, stream>>>(priors, targets, P, T, keys);
    best_prior_unpack_kernel<<<(BT + 255) / 256, 256, 0, stream>>>(keys, T, BT,
                                                                   bpi, valid, any_valid);

    dim3 g3((P + 255) / 256, B);
    match_loss_kernel<<<g3, 256, 0, stream>>>(priors, targets, loc_data, conf_data,
                                              landm_data, bpi, valid, any_valid,
                                              P, T, rank_loss, num_pos, total_pos1, acc);

    topk_kernel<<<B, 1024, 0, stream>>>(rank_loss, num_pos, P, acc);

    finalize_kernel<<<1, 1, 0, stream>>>(num_pos, total_pos1, acc, B, out);
}